// Round 5
// baseline (406.634 us; speedup 1.0000x reference)
//
#include <hip/hip_runtime.h>
#include <math.h>

#define N_ROWS 65536
#define K_CODES 1024
#define D_DIM 256
#define TAU 2e-3f

// ws layout (bytes), ~1.53 MB total
#define WS_NFLAG   0         // unsigned
#define WS_CSQ     16        // float[1024]
#define WS_CSQD    4112      // double[1024] (8-aligned)
#define WS_COUNTS  12304     // unsigned[1024]
#define WS_MINIDX  16400     // int[65536]
#define WS_LIST    278544    // int[65536]
#define WS_PART    540688    // double[512]
#define WS_CBH_HI  544784    // _Float16[1024*256] (16-aligned)
#define WS_CBH_LO  1069072   // _Float16[1024*256] (16-aligned)
// d_out scratch (floats): xh f16 [0,8388608); xl f16 [8388608,16777216);
// xsq float[65536] at [16777218,16842754). All consumed before k_out overwrites.

typedef _Float16 f16x8 __attribute__((ext_vector_type(8)));
typedef float    f32x4 __attribute__((ext_vector_type(4)));

__device__ __forceinline__ void gl_lds16(const _Float16* g, _Float16* l) {
    __builtin_amdgcn_global_load_lds(
        (const __attribute__((address_space(1))) unsigned int*)g,
        (__attribute__((address_space(3))) unsigned int*)l, 16, 0, 0);
}

// ---- prep: split fp32 -> (hi,lo) f16 for x and cb; xsq/csq/csqd; zero counts/nflag
__global__ __launch_bounds__(256) void k_prep(
    const float* __restrict__ x, const float* __restrict__ cb,
    _Float16* __restrict__ xhi, _Float16* __restrict__ xlo,
    _Float16* __restrict__ chi, _Float16* __restrict__ clo,
    float* __restrict__ xsq, float* __restrict__ csq, double* __restrict__ csqd,
    unsigned* __restrict__ counts, unsigned* __restrict__ nflag)
{
    const int b = blockIdx.x;
    const int t = threadIdx.x;
    if (b < 8192) {
        const long idx8 = (long)b * 2048 + t * 8;
        float4 v0 = *(const float4*)(x + idx8);
        float4 v1 = *(const float4*)(x + idx8 + 4);
        float vv[8] = {v0.x, v0.y, v0.z, v0.w, v1.x, v1.y, v1.z, v1.w};
        f16x8 h, l;
#pragma unroll
        for (int i = 0; i < 8; ++i) {
            h[i] = (_Float16)vv[i];
            l[i] = (_Float16)(vv[i] - (float)h[i]);
        }
        *(f16x8*)(xhi + idx8) = h;
        *(f16x8*)(xlo + idx8) = l;
        float sq = 0.f;
#pragma unroll
        for (int i = 0; i < 8; ++i) sq += vv[i] * vv[i];
        for (int off = 16; off > 0; off >>= 1) sq += __shfl_down(sq, off, 32);
        if ((t & 31) == 0) xsq[b * 8 + (t >> 5)] = sq;
    } else {
        const int b2 = b - 8192;
        const long idx8 = (long)b2 * 2048 + t * 8;
        float4 v0 = *(const float4*)(cb + idx8);
        float4 v1 = *(const float4*)(cb + idx8 + 4);
        float vv[8] = {v0.x, v0.y, v0.z, v0.w, v1.x, v1.y, v1.z, v1.w};
        f16x8 h, l;
#pragma unroll
        for (int i = 0; i < 8; ++i) {
            h[i] = (_Float16)vv[i];
            l[i] = (_Float16)(vv[i] - (float)h[i]);
        }
        *(f16x8*)(chi + idx8) = h;
        *(f16x8*)(clo + idx8) = l;
        double sqd = 0.0;
#pragma unroll
        for (int i = 0; i < 8; ++i) sqd += (double)vv[i] * vv[i];
        for (int off = 16; off > 0; off >>= 1) sqd += __shfl_down(sqd, off, 32);
        if ((t & 31) == 0) {
            csqd[b2 * 8 + (t >> 5)] = sqd;
            csq[b2 * 8 + (t >> 5)] = (float)sqd;
        }
        if (b2 < 4) counts[b2 * 256 + t] = 0u;
        if (b2 == 0 && t == 0) *nflag = 0u;
    }
}

__device__ __forceinline__ void merge2(float& m1, int& i1, float& m2,
                                       float om1, int oi1, float om2) {
    float hi  = fmaxf(m1, om1);
    float lo2 = fminf(m2, om2);
    bool take = (om1 < m1) || (om1 == m1 && oi1 < i1);
    if (take) { m1 = om1; i1 = oi1; }
    m2 = fminf(hi, lo2);
}

// ---- main: 128 rows x 1024 codes per block; split-f16 3-product MFMA;
// 2x2 wave grid (each wave 64 rows x 64 codes); top-2 argmin; loss partials.
__global__ __launch_bounds__(256) void k_main(
    const _Float16* __restrict__ xhi, const _Float16* __restrict__ xlo,
    const _Float16* __restrict__ chi, const _Float16* __restrict__ clo,
    const float* __restrict__ csq, const float* __restrict__ xsq,
    int* __restrict__ min_idx, int* __restrict__ list,
    unsigned* __restrict__ nflag, double* __restrict__ partials)
{
    __shared__ __attribute__((aligned(16))) _Float16 AsH[128 * 32]; // 8 KB
    __shared__ __attribute__((aligned(16))) _Float16 AsL[128 * 32];
    __shared__ __attribute__((aligned(16))) _Float16 BsH[128 * 32];
    __shared__ __attribute__((aligned(16))) _Float16 BsL[128 * 32];
    __shared__ float m1s[2][128];
    __shared__ float m2s[2][128];
    __shared__ int   i1s[2][128];
    __shared__ double red[128];

    const int tid  = threadIdx.x;
    const int w    = tid >> 6;
    const int lane = tid & 63;
    const int rlow = lane & 15;
    const int quad = lane >> 4;
    const int rtile = (w & 1) * 64;       // wave's row offset in block
    const int ctile = (w >> 1) * 64;      // wave's code offset in k-tile
    const long n0  = (long)blockIdx.x * 128;

    float sm1[16], sm2[16];
    int   si1[16];
#pragma unroll
    for (int s = 0; s < 16; s++) { sm1[s] = INFINITY; sm2[s] = INFINITY; si1[s] = 0; }

    for (int kt = 0; kt < 8; ++kt) {
        const int kbase = kt * 128;
        f32x4 acc[16];
        const f32x4 z = {0.f, 0.f, 0.f, 0.f};
#pragma unroll
        for (int t = 0; t < 16; t++) acc[t] = z;

        for (int d0 = 0; d0 < 256; d0 += 32) {
            __syncthreads();
#pragma unroll
            for (int r = 0; r < 2; ++r) {
                int o = r * 256 + tid;          // 0..511
                int row = o >> 2;               // 0..127
                int part = o & 3;               // 8 f16 each
                long xoff = (n0 + row) * 256 + d0 + part * 8;
                long coff = (long)(kbase + row) * 256 + d0 + part * 8;
                gl_lds16(xhi + xoff, AsH + o * 8);
                gl_lds16(xlo + xoff, AsL + o * 8);
                gl_lds16(chi + coff, BsH + o * 8);
                gl_lds16(clo + coff, BsL + o * 8);
            }
            __syncthreads();

            f16x8 ah[4], al[4], bh[4], bl[4];
#pragma unroll
            for (int i = 0; i < 4; ++i) {
                int ar = (rtile + i * 16 + rlow) * 32 + quad * 8;
                ah[i] = *(const f16x8*)&AsH[ar];
                al[i] = *(const f16x8*)&AsL[ar];
                int br = (ctile + i * 16 + rlow) * 32 + quad * 8;
                bh[i] = *(const f16x8*)&BsH[br];
                bl[i] = *(const f16x8*)&BsL[br];
            }
#pragma unroll
            for (int i = 0; i < 4; ++i)
#pragma unroll
                for (int j = 0; j < 4; ++j)
                    acc[i * 4 + j] = __builtin_amdgcn_mfma_f32_16x16x32_f16(
                        ah[i], bh[j], acc[i * 4 + j], 0, 0, 0);
#pragma unroll
            for (int i = 0; i < 4; ++i)
#pragma unroll
                for (int j = 0; j < 4; ++j)
                    acc[i * 4 + j] = __builtin_amdgcn_mfma_f32_16x16x32_f16(
                        ah[i], bl[j], acc[i * 4 + j], 0, 0, 0);
#pragma unroll
            for (int i = 0; i < 4; ++i)
#pragma unroll
                for (int j = 0; j < 4; ++j)
                    acc[i * 4 + j] = __builtin_amdgcn_mfma_f32_16x16x32_f16(
                        al[i], bh[j], acc[i * 4 + j], 0, 0, 0);
        }

#pragma unroll
        for (int j = 0; j < 4; ++j) {
            const int code = kbase + ctile + j * 16 + rlow;
            const float csj = csq[code];
#pragma unroll
            for (int i = 0; i < 4; ++i)
#pragma unroll
                for (int v = 0; v < 4; ++v) {
                    const int s = i * 4 + v;
                    float val = fmaf(-2.f, acc[i * 4 + j][v], csj);
                    bool lt = val < sm1[s];
                    sm2[s] = fminf(fmaxf(val, sm1[s]), sm2[s]);
                    si1[s] = lt ? code : si1[s];
                    sm1[s] = fminf(val, sm1[s]);
                }
        }
    }

    // butterfly over the 16 rlow lanes (codes)
#pragma unroll
    for (int s = 0; s < 16; ++s) {
#pragma unroll
        for (int m = 1; m < 16; m <<= 1) {
            float om1 = __shfl_xor(sm1[s], m, 64);
            float om2 = __shfl_xor(sm2[s], m, 64);
            int   oi1 = __shfl_xor(si1[s], m, 64);
            merge2(sm1[s], si1[s], sm2[s], om1, oi1, om2);
        }
    }

    // stash per-code-half results: g = which 64-code group this wave owned
    if (rlow == 0) {
        const int g = w >> 1;
#pragma unroll
        for (int i = 0; i < 4; ++i)
#pragma unroll
            for (int v = 0; v < 4; ++v) {
                const int s = i * 4 + v;
                const int rl = (w & 1) * 64 + i * 16 + quad * 4 + v;
                m1s[g][rl] = sm1[s];
                m2s[g][rl] = sm2[s];
                i1s[g][rl] = si1[s];
            }
    }
    __syncthreads();

    // merge the two code halves per row; outputs + flags + loss partials
    if (tid < 128) {
        float m1 = m1s[0][tid], m2 = m2s[0][tid];
        int   i1 = i1s[0][tid];
        merge2(m1, i1, m2, m1s[1][tid], i1s[1][tid], m2s[1][tid]);
        const long n = n0 + tid;
        min_idx[n] = i1;
        if (m2 - m1 < TAU) { unsigned p = atomicAdd(nflag, 1u); list[p] = (int)n; }
        red[tid] = (double)xsq[n] + (double)m1;
    }
    __syncthreads();
    for (int off = 64; off > 0; off >>= 1) {
        if (tid < off) red[tid] += red[tid + off];
        __syncthreads();
    }
    if (tid == 0) partials[blockIdx.x] = red[0];
}

// ---- exact fp64 re-rank, one block per flagged row (nf expected ~tens).
// d-chunk outer with x in registers -> minimal LDS traffic.
__global__ __launch_bounds__(256) void k_refine(
    const float* __restrict__ x, const float* __restrict__ cb,
    const double* __restrict__ csqd, const unsigned* __restrict__ nflag,
    const int* __restrict__ list, int* __restrict__ min_idx)
{
    __shared__ double xsd[D_DIM];   // 2 KB
    __shared__ double bv[256];
    __shared__ int    bi[256];
    const int tid = threadIdx.x;
    const unsigned nf = *nflag;

    for (unsigned it = blockIdx.x; it < nf; it += gridDim.x) {
        const int row = list[it];
        __syncthreads();
        if (tid < 64) {
            float4 v = *(const float4*)(x + (long)row * D_DIM + tid * 4);
            xsd[tid * 4]     = (double)v.x;
            xsd[tid * 4 + 1] = (double)v.y;
            xsd[tid * 4 + 2] = (double)v.z;
            xsd[tid * 4 + 3] = (double)v.w;
        }
        __syncthreads();

        // thread owns codes tid, tid+256, tid+512, tid+768
        double s[4] = {0.0, 0.0, 0.0, 0.0};
        for (int d = 0; d < D_DIM; d += 4) {
            double x0 = xsd[d], x1 = xsd[d + 1], x2 = xsd[d + 2], x3 = xsd[d + 3];
#pragma unroll
            for (int c = 0; c < 4; ++c) {
                float4 cv = *(const float4*)(cb + (long)(c * 256 + tid) * D_DIM + d);
                s[c] = fma(x0, (double)cv.x, s[c]);
                s[c] = fma(x1, (double)cv.y, s[c]);
                s[c] = fma(x2, (double)cv.z, s[c]);
                s[c] = fma(x3, (double)cv.w, s[c]);
            }
        }
        double best = 1e300; int bidx = 0;
#pragma unroll
        for (int c = 0; c < 4; ++c) {
            const int k = c * 256 + tid;
            double dist = fma(-2.0, s[c], csqd[k]);
            if (dist < best || (dist == best && k < bidx)) { best = dist; bidx = k; }
        }
        bv[tid] = best; bi[tid] = bidx;
        __syncthreads();
        for (int off = 128; off > 0; off >>= 1) {
            if (tid < off) {
                if (bv[tid + off] < bv[tid] ||
                    (bv[tid + off] == bv[tid] && bi[tid + off] < bi[tid])) {
                    bv[tid] = bv[tid + off]; bi[tid] = bi[tid + off];
                }
            }
            __syncthreads();
        }
        if (tid == 0) min_idx[row] = bi[0];
        __syncthreads();
    }
}

// ---- gather quantized rows, histogram, index output
__global__ __launch_bounds__(256) void k_out(
    const float* __restrict__ cb, const int* __restrict__ min_idx,
    float* __restrict__ out, unsigned* __restrict__ counts)
{
    const int tid  = threadIdx.x;
    const int wave = tid >> 6;
    const int lane = tid & 63;
    const long n = (long)blockIdx.x * 4 + wave;
    const int idx = min_idx[n];

    float4 q = *(const float4*)(cb + (long)idx * D_DIM + lane * 4);
    *(float4*)(out + n * D_DIM + lane * 4) = q;

    if (lane == 0) {
        atomicAdd(&counts[idx], 1u);
        out[16777218L + n] = (float)idx;
    }
}

__global__ void k_final(const double* __restrict__ partials,
                        const unsigned* __restrict__ counts, float* __restrict__ out)
{
    __shared__ double red[256];
    const int tid = threadIdx.x;

    red[tid] = partials[tid] + partials[tid + 256];
    __syncthreads();
    for (int off = 128; off > 0; off >>= 1) { if (tid < off) red[tid] += red[tid + off]; __syncthreads(); }
    double loss = red[0] / (double)((long)N_ROWS * D_DIM);
    __syncthreads();

    double h = 0.0;
    for (int k = tid; k < K_CODES; k += 256) {
        double p = (double)counts[k] / (double)N_ROWS;
        h += p * log(p + 1e-10);
    }
    red[tid] = h;
    __syncthreads();
    for (int off = 128; off > 0; off >>= 1) { if (tid < off) red[tid] += red[tid + off]; __syncthreads(); }

    if (tid == 0) {
        out[16777216] = (float)loss;
        out[16777217] = (float)exp(-red[0]);
    }
}

extern "C" void kernel_launch(void* const* d_in, const int* in_sizes, int n_in,
                              void* d_out, int out_size, void* d_ws, size_t ws_size,
                              hipStream_t stream)
{
    const float* x  = (const float*)d_in[0];
    const float* cb = (const float*)d_in[1];
    float* out = (float*)d_out;
    char*  ws  = (char*)d_ws;

    unsigned*  nflag    = (unsigned*)(ws + WS_NFLAG);
    float*     csq      = (float*)(ws + WS_CSQ);
    double*    csqd     = (double*)(ws + WS_CSQD);
    unsigned*  counts   = (unsigned*)(ws + WS_COUNTS);
    int*       min_idx  = (int*)(ws + WS_MINIDX);
    int*       list     = (int*)(ws + WS_LIST);
    double*    partials = (double*)(ws + WS_PART);
    _Float16*  chi      = (_Float16*)(ws + WS_CBH_HI);
    _Float16*  clo      = (_Float16*)(ws + WS_CBH_LO);
    _Float16*  xhi      = (_Float16*)d_out;                     // floats [0, 8388608)
    _Float16*  xlo      = ((_Float16*)d_out) + 16777216L;       // floats [8388608, 16777216)
    float*     xsq      = out + 16777218L;

    hipLaunchKernelGGL(k_prep,   dim3(8192 + 128), dim3(256), 0, stream,
                       x, cb, xhi, xlo, chi, clo, xsq, csq, csqd, counts, nflag);
    hipLaunchKernelGGL(k_main,   dim3(N_ROWS / 128), dim3(256), 0, stream,
                       xhi, xlo, chi, clo, csq, xsq, min_idx, list, nflag, partials);
    hipLaunchKernelGGL(k_refine, dim3(256), dim3(256), 0, stream,
                       x, cb, csqd, nflag, list, min_idx);
    hipLaunchKernelGGL(k_out,    dim3(N_ROWS / 4), dim3(256), 0, stream,
                       cb, min_idx, out, counts);
    hipLaunchKernelGGL(k_final,  dim3(1), dim3(256), 0, stream, partials, counts, out);
}